// Round 1
// baseline (4674.495 us; speedup 1.0000x reference)
//
#include <hip/hip_runtime.h>
#include <hip/hip_bf16.h>
#include <stdint.h>

#define B_ 128
#define S_ 1024
#define H_ 256

typedef __attribute__((ext_vector_type(8))) short short8;
typedef __attribute__((ext_vector_type(4))) float f32x4;

__device__ __forceinline__ short f2bf(float f) {
    union { float f; uint32_t u; } v; v.f = f;
    uint32_t r = v.u + 0x7FFFu + ((v.u >> 16) & 1u);   // RNE
    return (short)(r >> 16);
}
__device__ __forceinline__ float bf2f(short s) {
    union { uint32_t u; float f; } v; v.u = ((uint32_t)(uint16_t)s) << 16;
    return v.f;
}
__device__ __forceinline__ f32x4 mfma16(short8 a, short8 b, f32x4 c) {
    return __builtin_amdgcn_mfma_f32_16x16x32_bf16(a, b, c, 0, 0, 0);
}
__device__ __forceinline__ float sigmoidf_(float x) {
    return 1.0f / (1.0f + __expf(-x));
}
__device__ __forceinline__ float tanhf_(float x) {
    float xx = fminf(x, 15.0f);          // avoid inf/inf NaN
    float e = __expf(2.0f * xx);
    return (e - 1.0f) / (e + 1.0f);
}

// Load one B-fragment (16x16x32 bf16 MFMA) from a row-major fp32 weight W[n][k]:
// lane holds B[k][n] with n = (lane&15) offset by caller, k = ko + 0..7 (8 consecutive).
__device__ __forceinline__ short8 loadfrag_f32(const float* __restrict__ W, int n, int ko) {
    const float* p = W + (size_t)n * 256 + ko;
    float4 lo = *(const float4*)p;
    float4 hi = *(const float4*)(p + 4);
    short8 f;
    f[0] = f2bf(lo.x); f[1] = f2bf(lo.y); f[2] = f2bf(lo.z); f[3] = f2bf(lo.w);
    f[4] = f2bf(hi.x); f[5] = f2bf(hi.y); f[6] = f2bf(hi.z); f[7] = f2bf(hi.w);
    return f;
}

// ---------------- kernel 0: convert x-side weights fp32 -> bf16 ----------------
__global__ void cvt_wx_kernel(const float* __restrict__ Wz, const float* __restrict__ Wr,
                              const float* __restrict__ Wc, short* __restrict__ out) {
    int i = blockIdx.x * 256 + threadIdx.x;      // 65536 elems per matrix, grid 256x256
    out[i]           = f2bf(Wz[i]);
    out[65536 + i]   = f2bf(Wr[i]);
    out[131072 + i]  = f2bf(Wc[i]);
}

// ---------------- kernel 1: input projections xz/xr/xc = x*W^T + b -------------
// proj layout: [3][S][B][H] bf16
__global__ __launch_bounds__(256, 1) void proj_kernel(
    const float* __restrict__ x,      // [B][S][H] fp32
    const short* __restrict__ Wx,     // [3][256][256] bf16
    const float* __restrict__ bz, const float* __restrict__ br, const float* __restrict__ bc,
    short* __restrict__ proj) {
    const int tid = threadIdx.x;
    const int wave = tid >> 6, lane = tid & 63;
    const int l15 = lane & 15, quad = lane >> 4;
    const int b0 = (blockIdx.x & 7) * 16;        // 8 batch tiles
    const int t0 = (blockIdx.x >> 3) * 2;        // 512 t tiles (2 t each)
    const int colbase = wave * 64;               // 4 waves x 64 cols

    f32x4 acc[2][4][3];
    const f32x4 z4 = {0.f, 0.f, 0.f, 0.f};
#pragma unroll
    for (int tt = 0; tt < 2; ++tt)
#pragma unroll
        for (int ct = 0; ct < 4; ++ct)
#pragma unroll
            for (int g = 0; g < 3; ++g) acc[tt][ct][g] = z4;

#pragma unroll
    for (int kc = 0; kc < 8; ++kc) {
        const int koff = kc * 32 + quad * 8;
        short8 afrag[2];
#pragma unroll
        for (int tt = 0; tt < 2; ++tt) {
            const float* xp = x + ((size_t)(b0 + l15) * S_ + (t0 + tt)) * H_ + koff;
            float4 lo = *(const float4*)xp;
            float4 hi = *(const float4*)(xp + 4);
            short8 f;
            f[0] = f2bf(lo.x); f[1] = f2bf(lo.y); f[2] = f2bf(lo.z); f[3] = f2bf(lo.w);
            f[4] = f2bf(hi.x); f[5] = f2bf(hi.y); f[6] = f2bf(hi.z); f[7] = f2bf(hi.w);
            afrag[tt] = f;
        }
#pragma unroll
        for (int g = 0; g < 3; ++g) {
#pragma unroll
            for (int ct = 0; ct < 4; ++ct) {
                const int n = colbase + ct * 16 + l15;
                short8 bfrag = *(const short8*)(Wx + (size_t)g * 65536 + (size_t)n * 256 + koff);
#pragma unroll
                for (int tt = 0; tt < 2; ++tt)
                    acc[tt][ct][g] = mfma16(afrag[tt], bfrag, acc[tt][ct][g]);
            }
        }
    }
    // epilogue: + bias, cast bf16, store [g][t][b][h]
#pragma unroll
    for (int g = 0; g < 3; ++g) {
        const float* bp = (g == 0) ? bz : (g == 1) ? br : bc;
#pragma unroll
        for (int ct = 0; ct < 4; ++ct) {
            const int n = colbase + ct * 16 + l15;
            const float bias = bp[n];
#pragma unroll
            for (int tt = 0; tt < 2; ++tt) {
#pragma unroll
                for (int q = 0; q < 4; ++q) {
                    const int m = quad * 4 + q;   // C-layout: row=(lane>>4)*4+reg, col=lane&15
                    const float v = acc[tt][ct][g][q] + bias;
                    proj[((size_t)g * S_ + (t0 + tt)) * (B_ * H_) + (size_t)(b0 + m) * H_ + n] = f2bf(v);
                }
            }
        }
    }
}

// ---------------- kernel 2: the sequential GRU recurrence ----------------------
// 8 WGs x 512 threads. WG g owns batch rows 16g..16g+15 for all 1024 steps.
// Recurrent weights live as persistent MFMA B-fragments in VGPRs (192 regs/thread).
__global__ __launch_bounds__(512, 2) void gru_kernel(
    const float* __restrict__ h0,
    const float* __restrict__ Wzh, const float* __restrict__ Wrh, const float* __restrict__ Wch,
    const short* __restrict__ proj,   // [3][S][B][H] bf16
    float* __restrict__ out) {        // [B][S][H] fp32
    const int tid = threadIdx.x;
    const int wave = tid >> 6, lane = tid & 63;   // 8 waves, each owns 32 cols
    const int l15 = lane & 15, quad = lane >> 4;
    const int b0 = blockIdx.x * 16;

    __shared__ __align__(16) short h_bf[16 * 264];   // h (bf16), padded rows: +8 to spread banks
    __shared__ __align__(16) short p_bf[16 * 264];   // r*h (bf16)
    __shared__ __align__(16) short xs[3 * 16 * 256]; // staged xz/xr/xc for current t (unpadded)

    // ---- persistent recurrent-weight fragments (cols = wave*32 + ct*16 + l15) ----
    short8 wz[2][8], wr[2][8], wc[2][8];
#pragma unroll
    for (int ct = 0; ct < 2; ++ct) {
        const int n = wave * 32 + ct * 16 + l15;
#pragma unroll
        for (int kc = 0; kc < 8; ++kc) {
            const int ko = kc * 32 + quad * 8;
            wz[ct][kc] = loadfrag_f32(Wzh, n, ko);
            wr[ct][kc] = loadfrag_f32(Wrh, n, ko);
            wc[ct][kc] = loadfrag_f32(Wch, n, ko);
        }
    }

    // ---- init: fp32 carry of h in registers (C-layout ownership), bf16 copy in LDS ----
    float carry[2][4];
#pragma unroll
    for (int ct = 0; ct < 2; ++ct)
#pragma unroll
        for (int q = 0; q < 4; ++q) {
            const int m = quad * 4 + q, n = wave * 32 + ct * 16 + l15;
            float h = h0[(size_t)(b0 + m) * H_ + n];
            carry[ct][q] = h;
            h_bf[m * 264 + n] = f2bf(h);
        }
    __syncthreads();

    const f32x4 z4 = {0.f, 0.f, 0.f, 0.f};

#pragma unroll 1
    for (int t = 0; t < S_; ++t) {
        // -------- stage x-projections for step t (16B per thread per gate) --------
        {
            const size_t base = (size_t)t * (B_ * H_) + (size_t)b0 * H_ + (size_t)tid * 8;
#pragma unroll
            for (int g = 0; g < 3; ++g) {
                const short8 v = *(const short8*)(proj + (size_t)g * S_ * B_ * H_ + base);
                *(short8*)(&xs[g * 4096 + tid * 8]) = v;
            }
        }
        // -------- z/r matvec: az/ar = h_prev @ W^T (A from LDS, B from regs) --------
        f32x4 az[2], ar[2];
        az[0] = az[1] = ar[0] = ar[1] = z4;
#pragma unroll
        for (int kc = 0; kc < 8; ++kc) {
            short8 a = *(const short8*)(&h_bf[l15 * 264 + kc * 32 + quad * 8]);
#pragma unroll
            for (int ct = 0; ct < 2; ++ct) {
                az[ct] = mfma16(a, wz[ct][kc], az[ct]);
                ar[ct] = mfma16(a, wr[ct][kc], ar[ct]);
            }
        }
        __syncthreads();   // B1: staging visible

        // -------- pointwise z, r; publish p = r*h_prev; prefetch xc into regs -----
#pragma unroll
        for (int ct = 0; ct < 2; ++ct)
#pragma unroll
            for (int q = 0; q < 4; ++q) {
                const int m = quad * 4 + q, n = wave * 32 + ct * 16 + l15;
                const float xz = bf2f(xs[m * 256 + n]);
                const float xr = bf2f(xs[4096 + m * 256 + n]);
                const float xc = bf2f(xs[8192 + m * 256 + n]);
                const float z = sigmoidf_(az[ct][q] + xz);
                const float r = sigmoidf_(ar[ct][q] + xr);
                az[ct][q] = z;    // reuse regs: az now holds z
                ar[ct][q] = xc;   // ar now holds xc
                p_bf[m * 264 + n] = f2bf(r * carry[ct][q]);
            }
        __syncthreads();   // B2: p ready

        // -------- c matvec: ac = (r*h) @ Wc^T --------
        f32x4 ac[2];
        ac[0] = ac[1] = z4;
#pragma unroll
        for (int kc = 0; kc < 8; ++kc) {
            short8 a = *(const short8*)(&p_bf[l15 * 264 + kc * 32 + quad * 8]);
#pragma unroll
            for (int ct = 0; ct < 2; ++ct)
                ac[ct] = mfma16(a, wc[ct][kc], ac[ct]);
        }
        // -------- h_new = (1-z)*h + z*tanh(xc + ac); write out + republish --------
#pragma unroll
        for (int ct = 0; ct < 2; ++ct)
#pragma unroll
            for (int q = 0; q < 4; ++q) {
                const int m = quad * 4 + q, n = wave * 32 + ct * 16 + l15;
                const float ht = tanhf_(ac[ct][q] + ar[ct][q]);
                const float z = az[ct][q];
                const float hn = (1.0f - z) * carry[ct][q] + z * ht;
                carry[ct][q] = hn;
                out[((size_t)(b0 + m) * S_ + t) * H_ + n] = hn;
                h_bf[m * 264 + n] = f2bf(hn);
            }
        __syncthreads();   // B3: h_bf ready for t+1 (also frees xs for re-staging)
    }
}

extern "C" void kernel_launch(void* const* d_in, const int* in_sizes, int n_in,
                              void* d_out, int out_size, void* d_ws, size_t ws_size,
                              hipStream_t stream) {
    const float* x    = (const float*)d_in[0];
    const float* h0   = (const float*)d_in[1];
    const float* Wz_x = (const float*)d_in[2];
    const float* bz   = (const float*)d_in[3];
    const float* Wz_h = (const float*)d_in[4];
    const float* Wr_x = (const float*)d_in[5];
    const float* br   = (const float*)d_in[6];
    const float* Wr_h = (const float*)d_in[7];
    const float* Wc_x = (const float*)d_in[8];
    const float* bc   = (const float*)d_in[9];
    const float* Wc_h = (const float*)d_in[10];
    float* out = (float*)d_out;

    // workspace layout: proj bf16 [3][S][B][H] (192 MB) then Wx bf16 [3][256][256]
    short* proj = (short*)d_ws;
    short* WxBf = proj + (size_t)3 * S_ * B_ * H_;

    cvt_wx_kernel<<<256, 256, 0, stream>>>(Wz_x, Wr_x, Wc_x, WxBf);
    proj_kernel<<<4096, 256, 0, stream>>>(x, WxBf, bz, br, bc, proj);
    gru_kernel<<<8, 512, 0, stream>>>(h0, Wz_h, Wr_h, Wc_h, proj, out);
}

// Round 2
// 2636.221 us; speedup vs baseline: 1.7732x; 1.7732x over previous
//
#include <hip/hip_runtime.h>
#include <hip/hip_bf16.h>
#include <stdint.h>

#define B_ 128
#define S_ 1024
#define H_ 256

typedef __attribute__((ext_vector_type(8))) short short8;
typedef __attribute__((ext_vector_type(4))) float f32x4;

__device__ __forceinline__ short f2bf(float f) {
    union { float f; uint32_t u; } v; v.f = f;
    uint32_t r = v.u + 0x7FFFu + ((v.u >> 16) & 1u);   // RNE
    return (short)(r >> 16);
}
__device__ __forceinline__ float bf2f(short s) {
    union { uint32_t u; float f; } v; v.u = ((uint32_t)(uint16_t)s) << 16;
    return v.f;
}
__device__ __forceinline__ f32x4 mfma16(short8 a, short8 b, f32x4 c) {
    return __builtin_amdgcn_mfma_f32_16x16x32_bf16(a, b, c, 0, 0, 0);
}
__device__ __forceinline__ float fast_sigmoid(float x) {
    float e = __expf(-x);                       // -x>88 -> inf -> rcp -> 0, correct tail
    return __builtin_amdgcn_rcpf(1.0f + e);
}
__device__ __forceinline__ float fast_tanh(float x) {
    float xx = fminf(x, 15.0f);                 // avoid inf/inf
    float e = __expf(2.0f * xx);
    return (e - 1.0f) * __builtin_amdgcn_rcpf(e + 1.0f);
}

// async global -> LDS, 16 bytes per lane. LDS dest semantics: wave-uniform base + lane*16.
__device__ __forceinline__ void async_g2l(const void* g, void* l) {
    __builtin_amdgcn_global_load_lds((const __attribute__((address_space(1))) unsigned int*)g,
                                     (__attribute__((address_space(3))) unsigned int*)l,
                                     16, 0, 0);
}

// Load one B-fragment (16x16x32 bf16) from row-major fp32 W[n][k]:
// lane (l15,quad) holds B[k=ko..ko+7][n], n supplied by caller.
__device__ __forceinline__ short8 loadfrag_f32(const float* __restrict__ W, int n, int ko) {
    const float* p = W + (size_t)n * 256 + ko;
    float4 lo = *(const float4*)p;
    float4 hi = *(const float4*)(p + 4);
    short8 f;
    f[0] = f2bf(lo.x); f[1] = f2bf(lo.y); f[2] = f2bf(lo.z); f[3] = f2bf(lo.w);
    f[4] = f2bf(hi.x); f[5] = f2bf(hi.y); f[6] = f2bf(hi.z); f[7] = f2bf(hi.w);
    return f;
}

// ---- XOR-swizzled 16x256 bf16 tile helpers (16B-chunk swizzle: chunk ^= row&7) ----
// b128 A-fragment reads stay at the free 2-way minimum; scalar b16 writes spread to <=2-way.
__device__ __forceinline__ int swz_idx(int m, int n) {           // short index
    int chunk = n >> 3;
    int chunkp = (chunk & ~7) | ((chunk ^ m) & 7);
    return m * 256 + chunkp * 8 + (n & 7);
}
__device__ __forceinline__ short8 read_frag(const short* base, int row, int kc, int quad) {
    int chunk = kc * 4 + quad;
    int chunkp = (chunk & ~7) | ((chunk ^ row) & 7);
    return *(const short8*)(base + row * 256 + chunkp * 8);
}

// ---------------- kernel 0: convert x-side weights fp32 -> bf16 ----------------
__global__ void cvt_wx_kernel(const float* __restrict__ Wz, const float* __restrict__ Wr,
                              const float* __restrict__ Wc, short* __restrict__ out) {
    int i = blockIdx.x * 256 + threadIdx.x;
    out[i]          = f2bf(Wz[i]);
    out[65536 + i]  = f2bf(Wr[i]);
    out[131072 + i] = f2bf(Wc[i]);
}

// ---------------- kernel 1: input projections, stored as gru-ready records -----
// proj record layout: [t][btile(8)][gate(3)][tid(512)] : short8 (16B), where the
// 8 bf16 in a record are exactly gru-thread tid's (ct,q) values in C-layout.
__global__ __launch_bounds__(256, 1) void proj_kernel(
    const float* __restrict__ x,      // [B][S][H] fp32
    const short* __restrict__ Wx,     // [3][256][256] bf16
    const float* __restrict__ bz, const float* __restrict__ br, const float* __restrict__ bc,
    short8* __restrict__ proj) {
    const int tid = threadIdx.x;
    const int wave = tid >> 6, lane = tid & 63;   // 4 waves, 64 cols each
    const int l15 = lane & 15, quad = lane >> 4;
    const int bt = blockIdx.x & 7;
    const int b0 = bt * 16;
    const int t0 = (blockIdx.x >> 3) * 2;
    const int colbase = wave * 64;

    f32x4 acc[2][4][3];
    const f32x4 z4 = {0.f, 0.f, 0.f, 0.f};
#pragma unroll
    for (int tt = 0; tt < 2; ++tt)
#pragma unroll
        for (int ct = 0; ct < 4; ++ct)
#pragma unroll
            for (int g = 0; g < 3; ++g) acc[tt][ct][g] = z4;

#pragma unroll
    for (int kc = 0; kc < 8; ++kc) {
        const int koff = kc * 32 + quad * 8;
        short8 afrag[2];
#pragma unroll
        for (int tt = 0; tt < 2; ++tt) {
            const float* xp = x + ((size_t)(b0 + l15) * S_ + (t0 + tt)) * H_ + koff;
            float4 lo = *(const float4*)xp;
            float4 hi = *(const float4*)(xp + 4);
            short8 f;
            f[0] = f2bf(lo.x); f[1] = f2bf(lo.y); f[2] = f2bf(lo.z); f[3] = f2bf(lo.w);
            f[4] = f2bf(hi.x); f[5] = f2bf(hi.y); f[6] = f2bf(hi.z); f[7] = f2bf(hi.w);
            afrag[tt] = f;
        }
#pragma unroll
        for (int g = 0; g < 3; ++g) {
#pragma unroll
            for (int ct = 0; ct < 4; ++ct) {
                const int n = colbase + ct * 16 + l15;
                short8 bfrag = *(const short8*)(Wx + (size_t)g * 65536 + (size_t)n * 256 + koff);
#pragma unroll
                for (int tt = 0; tt < 2; ++tt)
                    acc[tt][ct][g] = mfma16(afrag[tt], bfrag, acc[tt][ct][g]);
            }
        }
    }
    // epilogue: +bias, pack per-gru-thread records, coalesced short8 stores
#pragma unroll
    for (int g = 0; g < 3; ++g) {
        const float* bp = (g == 0) ? bz : (g == 1) ? br : bc;
#pragma unroll
        for (int tt = 0; tt < 2; ++tt) {
#pragma unroll
            for (int rec = 0; rec < 2; ++rec) {
                short8 v;
#pragma unroll
                for (int ctg = 0; ctg < 2; ++ctg) {
                    const int ctp = rec * 2 + ctg;
                    const int n = colbase + ctp * 16 + l15;
                    const float bias = bp[n];
#pragma unroll
                    for (int q = 0; q < 4; ++q)
                        v[ctg * 4 + q] = f2bf(acc[tt][ctp][g][q] + bias);
                }
                const int tid_g = (wave * 2 + rec) * 64 + lane;
                proj[(((size_t)(t0 + tt) * 8 + bt) * 3 + g) * 512 + tid_g] = v;
            }
        }
    }
}

// ---------------- kernel 2: the sequential GRU recurrence ----------------------
// 8 WGs x 512 threads; WG owns 16 batch rows. Weights persistent in regs/AGPRs.
// 2 barriers/step; x-projections async-staged into LDS records one step ahead.
__global__ __launch_bounds__(512, 2) void gru_kernel(
    const float* __restrict__ h0,
    const float* __restrict__ Wzh, const float* __restrict__ Wrh, const float* __restrict__ Wch,
    const short8* __restrict__ proj,
    float* __restrict__ out) {        // [B][S][H] fp32
    const int tid = threadIdx.x;
    const int wave = tid >> 6, lane = tid & 63;   // 8 waves x 32 cols
    const int l15 = lane & 15, quad = lane >> 4;
    const int bt = blockIdx.x;
    const int b0 = bt * 16;

    __shared__ __align__(16) short h_bf[16 * 256];       // swizzled
    __shared__ __align__(16) short p_bf[16 * 256];       // swizzled
    __shared__ __align__(16) short xs[2][3][512 * 8];    // tid-linear records, dbuf

    // ---- persistent recurrent-weight fragments ----
    short8 wz[2][8], wr[2][8], wc[2][8];
#pragma unroll
    for (int ct = 0; ct < 2; ++ct) {
        const int n = wave * 32 + ct * 16 + l15;
#pragma unroll
        for (int kc = 0; kc < 8; ++kc) {
            const int ko = kc * 32 + quad * 8;
            wz[ct][kc] = loadfrag_f32(Wzh, n, ko);
            wr[ct][kc] = loadfrag_f32(Wrh, n, ko);
            wc[ct][kc] = loadfrag_f32(Wch, n, ko);
        }
    }

    // ---- init fp32 carry + publish h (swizzled) ----
    float carry[2][4];
#pragma unroll
    for (int ct = 0; ct < 2; ++ct)
#pragma unroll
        for (int q = 0; q < 4; ++q) {
            const int m = quad * 4 + q, n = wave * 32 + ct * 16 + l15;
            float h = h0[(size_t)(b0 + m) * H_ + n];
            carry[ct][q] = h;
            h_bf[swz_idx(m, n)] = f2bf(h);
        }

    // ---- prefetch t=0 records ----
#pragma unroll
    for (int g = 0; g < 3; ++g)
        async_g2l(proj + (((size_t)0 * 8 + bt) * 3 + g) * 512 + tid, &xs[0][g][wave * 64 * 8]);
    __syncthreads();   // drains vmcnt + publishes h_bf

    const f32x4 z4 = {0.f, 0.f, 0.f, 0.f};

#pragma unroll 1
    for (int t = 0; t < S_; ++t) {
        const int buf = t & 1, nbuf = buf ^ 1;
        // -------- issue async prefetch of step t+1 records --------
        const int tn = (t + 1 < S_) ? (t + 1) : t;
#pragma unroll
        for (int g = 0; g < 3; ++g)
            async_g2l(proj + (((size_t)tn * 8 + bt) * 3 + g) * 512 + tid, &xs[nbuf][g][wave * 64 * 8]);

        // -------- z/r matvec: A from swizzled h_bf, B from regs --------
        f32x4 az[2], ar[2];
        az[0] = az[1] = ar[0] = ar[1] = z4;
#pragma unroll
        for (int kc = 0; kc < 8; ++kc) {
            short8 a = read_frag(h_bf, l15, kc, quad);
#pragma unroll
            for (int ct = 0; ct < 2; ++ct) {
                az[ct] = mfma16(a, wz[ct][kc], az[ct]);
                ar[ct] = mfma16(a, wr[ct][kc], ar[ct]);
            }
        }
        // -------- pointwise z, r; publish p = r*h (swizzled scalar writes) ----
        const short8 vz = *(const short8*)(&xs[buf][0][tid * 8]);
        const short8 vr = *(const short8*)(&xs[buf][1][tid * 8]);
#pragma unroll
        for (int ct = 0; ct < 2; ++ct)
#pragma unroll
            for (int q = 0; q < 4; ++q) {
                const int m = quad * 4 + q, n = wave * 32 + ct * 16 + l15;
                const int idx = ct * 4 + q;
                const float z = fast_sigmoid(az[ct][q] + bf2f(vz[idx]));
                const float r = fast_sigmoid(ar[ct][q] + bf2f(vr[idx]));
                az[ct][q] = z;   // az now holds z
                p_bf[swz_idx(m, n)] = f2bf(r * carry[ct][q]);
            }
        __syncthreads();   // B2: p ready (h_bf reads all done)

        // -------- c matvec: A = r*h from p_bf --------
        f32x4 ac[2];
        ac[0] = ac[1] = z4;
#pragma unroll
        for (int kc = 0; kc < 8; ++kc) {
            short8 a = read_frag(p_bf, l15, kc, quad);
#pragma unroll
            for (int ct = 0; ct < 2; ++ct)
                ac[ct] = mfma16(a, wc[ct][kc], ac[ct]);
        }
        // -------- epilogue: h_new, store out, republish h --------
        const short8 vc = *(const short8*)(&xs[buf][2][tid * 8]);
#pragma unroll
        for (int ct = 0; ct < 2; ++ct)
#pragma unroll
            for (int q = 0; q < 4; ++q) {
                const int m = quad * 4 + q, n = wave * 32 + ct * 16 + l15;
                const int idx = ct * 4 + q;
                const float ht = fast_tanh(ac[ct][q] + bf2f(vc[idx]));
                const float z = az[ct][q];
                const float hn = (1.0f - z) * carry[ct][q] + z * ht;
                carry[ct][q] = hn;
                __builtin_nontemporal_store(hn, &out[((size_t)(b0 + m) * S_ + t) * H_ + n]);
                h_bf[swz_idx(m, n)] = f2bf(hn);
            }
        __syncthreads();   // B3: h_bf/xs[buf] free, prefetched xs[nbuf] usable next
    }
}

extern "C" void kernel_launch(void* const* d_in, const int* in_sizes, int n_in,
                              void* d_out, int out_size, void* d_ws, size_t ws_size,
                              hipStream_t stream) {
    const float* x    = (const float*)d_in[0];
    const float* h0   = (const float*)d_in[1];
    const float* Wz_x = (const float*)d_in[2];
    const float* bz   = (const float*)d_in[3];
    const float* Wz_h = (const float*)d_in[4];
    const float* Wr_x = (const float*)d_in[5];
    const float* br   = (const float*)d_in[6];
    const float* Wr_h = (const float*)d_in[7];
    const float* Wc_x = (const float*)d_in[8];
    const float* bc   = (const float*)d_in[9];
    const float* Wc_h = (const float*)d_in[10];
    float* out = (float*)d_out;

    // ws: proj records [S][8][3][512] short8 (192 MiB), then Wx bf16 (384 KiB)
    short8* proj = (short8*)d_ws;
    short* WxBf = (short*)(proj + (size_t)S_ * 8 * 3 * 512);

    cvt_wx_kernel<<<256, 256, 0, stream>>>(Wz_x, Wr_x, Wc_x, WxBf);
    proj_kernel<<<4096, 256, 0, stream>>>(x, WxBf, bz, br, bc, proj);
    gru_kernel<<<8, 512, 0, stream>>>(h0, Wz_h, Wr_h, Wc_h, proj, out);
}